// Round 1
// baseline (561.592 us; speedup 1.0000x reference)
//
#include <hip/hip_runtime.h>
#include <hip/hip_bf16.h>
#include <math.h>

// ExpertPool: B=2,N=1024 -> T=2048 tokens, D=768, E=8, H=3072, top-K=2
#define T_TOK 2048
#define DIM   768
#define NEXP  8
#define HDIM  3072
#define MAXP  (T_TOK * 2)   // exactly 4096 (token,expert) pairs (top-2 routing)

typedef __attribute__((ext_vector_type(8))) short bfrag;   // 8 bf16 (4 VGPRs)
typedef __attribute__((ext_vector_type(4))) float f32x4;   // MFMA C/D

__device__ __forceinline__ unsigned short f2bf(float f) {
  union { float f; unsigned int u; } x; x.f = f;
  unsigned int r = x.u + 0x7fffu + ((x.u >> 16) & 1u);  // RNE
  return (unsigned short)(r >> 16);
}
__device__ __forceinline__ float bf2f(unsigned short h) {
  union { unsigned int u; float f; } x; x.u = ((unsigned int)h) << 16; return x.f;
}

// ---------------- routing: per-expert contiguous row lists ----------------
__global__ void k_route(const float* __restrict__ disp,
                        const float* __restrict__ comb,
                        int* __restrict__ meta,        // [0..7]=cnt, [8..15]=off
                        float* __restrict__ row_comb,
                        int* __restrict__ row_token) {
  __shared__ int s_cnt[NEXP], s_off[NEXP], s_cur[NEXP];
  int tid = threadIdx.x;
  if (tid < NEXP) s_cnt[tid] = 0;
  __syncthreads();
  for (int t = tid; t < T_TOK; t += blockDim.x)
    for (int e = 0; e < NEXP; ++e)
      if (disp[t * NEXP + e] > 0.f) atomicAdd(&s_cnt[e], 1);
  __syncthreads();
  if (tid == 0) {
    int acc = 0;
    for (int e = 0; e < NEXP; ++e) { s_off[e] = acc; acc += s_cnt[e]; }
  }
  __syncthreads();
  if (tid < NEXP) {
    s_cur[tid] = s_off[tid];
    meta[tid] = s_cnt[tid];
    meta[NEXP + tid] = s_off[tid];
  }
  __syncthreads();
  for (int t = tid; t < T_TOK; t += blockDim.x)
    for (int e = 0; e < NEXP; ++e)
      if (disp[t * NEXP + e] > 0.f) {
        int p = atomicAdd(&s_cur[e], 1);
        row_token[p] = t;
        row_comb[p] = comb[t * NEXP + e];
      }
}

// ---------------- GEMM 1: (gathered X) @ W^T -> bf16 (P,H) ----------------
// W is (E,H,D) row-major = (N,K) per expert: gemm_bt form.
// 128x128 tile, BK=32, 4 waves each 64x64 of 16x16x32 MFMAs, inline fp32->bf16.
__global__ __launch_bounds__(256, 2) void k_gemm_xw(
    const float* __restrict__ X,        // (T_TOK, DIM)
    const float* __restrict__ W,        // (NEXP, HDIM, DIM)
    const int* __restrict__ meta,
    const int* __restrict__ row_token,
    unsigned short* __restrict__ outb)  // (MAXP, HDIM) bf16 raw
{
  int e = blockIdx.z;
  int cnt = meta[e];
  int m0 = blockIdx.y * 128;
  if (m0 >= cnt) return;
  int off = meta[NEXP + e];
  int n0 = blockIdx.x * 128;

  __shared__ unsigned short As[128 * 32];
  __shared__ unsigned short Bs[128 * 32];

  int tid = threadIdx.x;
  int wid = tid >> 6, lane = tid & 63;
  int wm = (wid >> 1) * 64, wn = (wid & 1) * 64;
  int lr = lane & 15, quad = lane >> 4;

  // A gather rows: 1024 float4 chunks per K-step -> 4 rounds of 256
  int a_tok[4];
#pragma unroll
  for (int r = 0; r < 4; ++r) {
    int row = (tid + 256 * r) >> 3;
    int gr = m0 + row; if (gr >= cnt) gr = cnt - 1;  // safe clamp, rows discarded later
    a_tok[r] = row_token[off + gr];
  }

  const float* Wb = W + (size_t)e * ((size_t)HDIM * DIM);

  f32x4 zero4 = {0.f, 0.f, 0.f, 0.f};
  f32x4 acc[4][4];
#pragma unroll
  for (int i = 0; i < 4; ++i)
#pragma unroll
    for (int j = 0; j < 4; ++j) acc[i][j] = zero4;

  for (int k0 = 0; k0 < DIM; k0 += 32) {
    __syncthreads();
#pragma unroll
    for (int r = 0; r < 4; ++r) {
      int c = tid + 256 * r;
      int row = c >> 3, c4 = c & 7;
      float4 av = *(const float4*)(X + (size_t)a_tok[r] * DIM + k0 + c4 * 4);
      ushort4 ap;
      ap.x = f2bf(av.x); ap.y = f2bf(av.y); ap.z = f2bf(av.z); ap.w = f2bf(av.w);
      *(ushort4*)(&As[row * 32 + c4 * 4]) = ap;
      float4 bv = *(const float4*)(Wb + (size_t)(n0 + row) * DIM + k0 + c4 * 4);
      ushort4 bp;
      bp.x = f2bf(bv.x); bp.y = f2bf(bv.y); bp.z = f2bf(bv.z); bp.w = f2bf(bv.w);
      *(ushort4*)(&Bs[row * 32 + c4 * 4]) = bp;
    }
    __syncthreads();
    bfrag a[4], b[4];
#pragma unroll
    for (int i = 0; i < 4; ++i)
      a[i] = *(const bfrag*)(&As[(wm + i * 16 + lr) * 32 + quad * 8]);
#pragma unroll
    for (int j = 0; j < 4; ++j)
      b[j] = *(const bfrag*)(&Bs[(wn + j * 16 + lr) * 32 + quad * 8]);
#pragma unroll
    for (int i = 0; i < 4; ++i)
#pragma unroll
      for (int j = 0; j < 4; ++j)
        acc[i][j] = __builtin_amdgcn_mfma_f32_16x16x32_bf16(a[i], b[j], acc[i][j], 0, 0, 0);
  }

  // C/D: col = lane&15, row = quad*4 + reg (m89/m91 verified)
#pragma unroll
  for (int i = 0; i < 4; ++i)
#pragma unroll
    for (int rg = 0; rg < 4; ++rg) {
      int gr = m0 + wm + i * 16 + quad * 4 + rg;
      if (gr < cnt) {
        size_t base = (size_t)(off + gr) * HDIM + n0 + wn;
#pragma unroll
        for (int j = 0; j < 4; ++j)
          outb[base + j * 16 + lr] = f2bf(acc[i][j][rg]);
      }
    }
}

// ---------------- pointwise: u = gelu_exact(h) * v (in-place ok) ----------------
__global__ void k_gelu_mul(const unsigned short* h,
                           const unsigned short* __restrict__ v,
                           unsigned short* u) {
  size_t idx = ((size_t)blockIdx.x * blockDim.x + threadIdx.x) * 8;
  uint4 hv = *(const uint4*)(h + idx);
  uint4 vv = *(const uint4*)(v + idx);
  const unsigned short* hs = (const unsigned short*)&hv;
  const unsigned short* vs = (const unsigned short*)&vv;
  unsigned short res[8];
#pragma unroll
  for (int i = 0; i < 8; ++i) {
    float x = bf2f(hs[i]);
    float y = bf2f(vs[i]);
    float g = 0.5f * x * (1.0f + erff(x * 0.70710678118654752f));
    res[i] = f2bf(g * y);
  }
  *(uint4*)(u + idx) = *(uint4*)res;
}

// ---------------- GEMM 2: u @ Wo^T * scale*comb -> atomicAdd into out ----------------
__global__ __launch_bounds__(256, 2) void k_gemm_out(
    const unsigned short* __restrict__ U,  // (MAXP, HDIM) bf16
    const float* __restrict__ Wo,          // (NEXP, DIM, HDIM) = (N,K) per expert
    const float* __restrict__ scale,       // (NEXP)
    const int* __restrict__ meta,
    const int* __restrict__ row_token,
    const float* __restrict__ row_comb,
    float* __restrict__ out)               // (T_TOK, DIM), pre-zeroed
{
  int e = blockIdx.z;
  int cnt = meta[e];
  int m0 = blockIdx.y * 128;
  if (m0 >= cnt) return;
  int off = meta[NEXP + e];
  int n0 = blockIdx.x * 128;

  __shared__ unsigned short As[128 * 32];
  __shared__ unsigned short Bs[128 * 32];

  int tid = threadIdx.x;
  int wid = tid >> 6, lane = tid & 63;
  int wm = (wid >> 1) * 64, wn = (wid & 1) * 64;
  int lr = lane & 15, quad = lane >> 4;

  // A already bf16: 512 x 16B chunks per K-step -> 2 rounds of 256
  int a_grow[2];
#pragma unroll
  for (int r = 0; r < 2; ++r) {
    int row = (tid + 256 * r) >> 2;
    int gr = m0 + row; if (gr >= cnt) gr = cnt - 1;
    a_grow[r] = off + gr;
  }

  const float* Wb = Wo + (size_t)e * ((size_t)DIM * HDIM);

  f32x4 zero4 = {0.f, 0.f, 0.f, 0.f};
  f32x4 acc[4][4];
#pragma unroll
  for (int i = 0; i < 4; ++i)
#pragma unroll
    for (int j = 0; j < 4; ++j) acc[i][j] = zero4;

  for (int k0 = 0; k0 < HDIM; k0 += 32) {
    __syncthreads();
#pragma unroll
    for (int r = 0; r < 2; ++r) {
      int c = tid + 256 * r;
      int row = c >> 2, c8 = c & 3;
      uint4 av = *(const uint4*)(U + (size_t)a_grow[r] * HDIM + k0 + c8 * 8);
      *(uint4*)(&As[row * 32 + c8 * 8]) = av;
    }
#pragma unroll
    for (int r = 0; r < 4; ++r) {
      int c = tid + 256 * r;
      int row = c >> 3, c4 = c & 7;
      float4 bv = *(const float4*)(Wb + (size_t)(n0 + row) * HDIM + k0 + c4 * 4);
      ushort4 bp;
      bp.x = f2bf(bv.x); bp.y = f2bf(bv.y); bp.z = f2bf(bv.z); bp.w = f2bf(bv.w);
      *(ushort4*)(&Bs[row * 32 + c4 * 4]) = bp;
    }
    __syncthreads();
    bfrag a[4], b[4];
#pragma unroll
    for (int i = 0; i < 4; ++i)
      a[i] = *(const bfrag*)(&As[(wm + i * 16 + lr) * 32 + quad * 8]);
#pragma unroll
    for (int j = 0; j < 4; ++j)
      b[j] = *(const bfrag*)(&Bs[(wn + j * 16 + lr) * 32 + quad * 8]);
#pragma unroll
    for (int i = 0; i < 4; ++i)
#pragma unroll
      for (int j = 0; j < 4; ++j)
        acc[i][j] = __builtin_amdgcn_mfma_f32_16x16x32_bf16(a[i], b[j], acc[i][j], 0, 0, 0);
  }

  float sc = scale[e];
#pragma unroll
  for (int i = 0; i < 4; ++i)
#pragma unroll
    for (int rg = 0; rg < 4; ++rg) {
      int gr = m0 + wm + i * 16 + quad * 4 + rg;
      if (gr < cnt) {
        int grow = off + gr;
        float w = row_comb[grow] * sc;
        int tok = row_token[grow];
        float* ob = out + (size_t)tok * DIM + n0 + wn;
#pragma unroll
        for (int j = 0; j < 4; ++j)
          atomicAdd(ob + j * 16 + lr, acc[i][j][rg] * w);
      }
    }
}

extern "C" void kernel_launch(void* const* d_in, const int* in_sizes, int n_in,
                              void* d_out, int out_size, void* d_ws, size_t ws_size,
                              hipStream_t stream) {
  const float* tokens = (const float*)d_in[0];
  const float* disp   = (const float*)d_in[1];
  const float* comb   = (const float*)d_in[2];
  const float* Wg     = (const float*)d_in[3];
  const float* Wv     = (const float*)d_in[4];
  const float* Wo     = (const float*)d_in[5];
  const float* scale  = (const float*)d_in[6];
  float* out = (float*)d_out;

  char* ws = (char*)d_ws;
  int*   meta      = (int*)ws;                       // 16 ints used
  int*   row_token = (int*)(ws + 1024);              // 4096 ints
  float* row_comb  = (float*)(ws + 1024 + 16384);    // 4096 floats
  // bf16 intermediates: h at +1MB (24MB), v after it (24MB); u reuses h in-place
  unsigned short* hbuf = (unsigned short*)(ws + (1u << 20));
  unsigned short* vbuf = (unsigned short*)(ws + (1u << 20) + (size_t)MAXP * HDIM * 2);

  hipMemsetAsync(d_out, 0, (size_t)out_size * sizeof(float), stream);
  hipLaunchKernelGGL(k_route, dim3(1), dim3(256), 0, stream,
                     disp, comb, meta, row_comb, row_token);
  dim3 g1(HDIM / 128, T_TOK / 128, NEXP);  // (24,16,8); ~3/4 of M-tiles early-exit
  hipLaunchKernelGGL(k_gemm_xw, g1, dim3(256), 0, stream, tokens, Wg, meta, row_token, hbuf);
  hipLaunchKernelGGL(k_gemm_xw, g1, dim3(256), 0, stream, tokens, Wv, meta, row_token, vbuf);
  hipLaunchKernelGGL(k_gelu_mul, dim3(((size_t)MAXP * HDIM) / (256 * 8)), dim3(256), 0, stream,
                     hbuf, vbuf, hbuf);
  dim3 g2(DIM / 128, T_TOK / 128, NEXP);   // (6,16,8)
  hipLaunchKernelGGL(k_gemm_out, g2, dim3(256), 0, stream,
                     hbuf, Wo, scale, meta, row_token, row_comb, out);
}